// Round 5
// baseline (1139.540 us; speedup 1.0000x reference)
//
#include <hip/hip_runtime.h>
#include <hip/hip_fp16.h>
#include <hip/hip_cooperative_groups.h>

namespace cg = cooperative_groups;

#define H_A   2048
#define H_HP  4096
#define DEPTH 12

struct Half8 { __half2 a, b, c, d; };   // 16 B
struct Half4 { __half2 a, b; };         // 8 B

__device__ __forceinline__ float fsig_(float x) { return 1.0f / (1.0f + __expf(-x)); }
__device__ __forceinline__ float ftanh_(float x) {
    return 1.0f - 2.0f / (__expf(2.0f * x) + 1.0f);
}
__device__ __forceinline__ float dot4_(float4 a, float4 b) {
    return a.x * b.x + a.y * b.y + a.z * b.z + a.w * b.w;
}
__device__ __forceinline__ float dot8h_(Half8 w, float4 x0, float4 x1) {
    float2 wa = __half22float2(w.a), wb = __half22float2(w.b);
    float2 wc = __half22float2(w.c), wd = __half22float2(w.d);
    return wa.x * x0.x + wa.y * x0.y + wb.x * x0.z + wb.y * x0.w +
           wc.x * x1.x + wc.y * x1.y + wd.x * x1.z + wd.y * x1.w;
}
__device__ __forceinline__ Half4 cvt4_(float4 a) {
    Half4 h;
    h.a = __floats2half2_rn(a.x, a.y);
    h.b = __floats2half2_rn(a.z, a.w);
    return h;
}
__device__ __forceinline__ Half8 cvt8_(float4 a, float4 b) {
    Half8 h;
    h.a = __floats2half2_rn(a.x, a.y);
    h.b = __floats2half2_rn(a.z, a.w);
    h.c = __floats2half2_rn(b.x, b.y);
    h.d = __floats2half2_rn(b.z, b.w);
    return h;
}
__device__ __forceinline__ float waveReduceSum(float v) {
#pragma unroll
    for (int off = 32; off > 0; off >>= 1) v += __shfl_xor(v, off, 64);
    return v;
}
__device__ __forceinline__ void waveReduce4(float& a0, float& a1, float& a2, float& a3) {
#pragma unroll
    for (int off = 32; off > 0; off >>= 1) {
        a0 += __shfl_xor(a0, off, 64);
        a1 += __shfl_xor(a1, off, 64);
        a2 += __shfl_xor(a2, off, 64);
        a3 += __shfl_xor(a3, off, 64);
    }
}

struct Params {
    const float *x_a, *x_hp;
    const float *W_ih_a, *W_hh_a, *b_ih_a, *b_hh_a;
    const float *W_out_a, *b_out_a, *W_sum, *b_sum;
    const float *W_ih_hp, *W_hh_hp, *b_ih_hp, *b_hh_hp, *W_out_hp, *b_out_hp;
    __half *hW_ih_a, *hW_hh_a, *hW_sum, *hW_ih_hp, *hW_hh_hp, *hW_out_a, *hW_out_hp;
    float *gates_a, *h_sum, *gacc, *h_a, *c_a0, *c_a1, *h_hp, *c_hp;
    float *logits_a, *logits_hp, *a_vec, *out;
};

// ===========================================================================
// Persistent cooperative kernel: 12 steps x 3 grid.sync phases + epilogue.
// Grid-size agnostic (work loops stride by gridDim.x*4 waves); needs >=16
// blocks. Exact initial state hardcoded; fp32->fp16 conversion folded into
// first use (t=0 / t=1).
// ===========================================================================
__global__ __launch_bounds__(256) void decoder_persistent(Params p)
{
    cg::grid_group grid = cg::this_grid();
    __shared__ float sbuf[2056];      // P2: h_s[2048]; P3: p_all[512]+red[8]
    const int tid = threadIdx.x, lane = tid & 63, wv = tid >> 6;
    const int waveId = (blockIdx.x << 2) | wv;
    const int nw = (gridDim.x << 2);

    for (int t = 0; t < DEPTH; ++t) {
        // ---------------- P1: all big GEMVs (deps: previous step only) -----
        {
            const int limit = (t == 0) ? 26624 : 26880;
            for (int r = waveId; r < limit; r += nw) {
                if (r < 8192) {
                    float acc;
                    if (t == 0) {
                        float4 wf = ((const float4*)(p.W_ih_a + (size_t)r * 256))[lane];
                        ((Half4*)(p.hW_ih_a + (size_t)r * 256))[lane] = cvt4_(wf);
                        acc = (wf.x + wf.y + wf.z + wf.w) * (1.0f / 256.0f);
                        const float4* whf = (const float4*)(p.W_hh_a + (size_t)r * H_A);
                        const float4* xh = (const float4*)p.x_a;
                        Half4* dsth = (Half4*)(p.hW_hh_a + (size_t)r * H_A);
#pragma unroll
                        for (int it = 0; it < 8; ++it) {
                            int idx = it * 64 + lane;
                            float4 w = whf[idx];
                            dsth[idx] = cvt4_(w);
                            acc += dot4_(w, xh[idx]);
                        }
                    } else {
                        Half4 w = ((const Half4*)(p.hW_ih_a + (size_t)r * 256))[lane];
                        float4 x = ((const float4*)p.a_vec)[lane];
                        float2 w0 = __half22float2(w.a), w1 = __half22float2(w.b);
                        acc = w0.x * x.x + w0.y * x.y + w1.x * x.z + w1.y * x.w;
                        const Half8* wh = (const Half8*)(p.hW_hh_a + (size_t)r * H_A);
                        const float4* xh = (const float4*)p.h_a;
#pragma unroll
                        for (int it = 0; it < 4; ++it) {
                            int idx = it * 64 + lane;
                            acc += dot8h_(wh[idx], xh[2 * idx], xh[2 * idx + 1]);
                        }
                    }
                    acc = waveReduceSum(acc);
                    if (lane == 0) p.gates_a[r] = acc + p.b_ih_a[r] + p.b_hh_a[r];
                } else if (r < 10240) {
                    const int rr = r - 8192;
                    float acc = 0.0f;
                    if (t == 0) {
                        const float4* wf = (const float4*)(p.W_sum + (size_t)rr * H_HP);
                        const float4* xx = (const float4*)p.x_hp;
                        Half4* dsth = (Half4*)(p.hW_sum + (size_t)rr * H_HP);
#pragma unroll
                        for (int it = 0; it < 16; ++it) {
                            int idx = it * 64 + lane;
                            float4 w = wf[idx];
                            dsth[idx] = cvt4_(w);
                            acc += dot4_(w, xx[idx]);
                        }
                    } else {
                        const Half8* ww = (const Half8*)(p.hW_sum + (size_t)rr * H_HP);
                        const float4* xx = (const float4*)p.h_hp;
#pragma unroll
                        for (int it = 0; it < 8; ++it) {
                            int idx = it * 64 + lane;
                            acc += dot8h_(ww[idx], xx[2 * idx], xx[2 * idx + 1]);
                        }
                    }
                    acc = waveReduceSum(acc);
                    if (lane == 0) p.h_sum[rr] = fmaxf(acc + p.b_sum[rr], 0.0f);
                } else if (r < 26624) {
                    const int rg = r - 10240;
                    if (t == 0) {
                        const float4* wf = (const float4*)(p.W_hh_hp + (size_t)rg * H_HP);
                        Half4* dsth = (Half4*)(p.hW_hh_hp + (size_t)rg * H_HP);
#pragma unroll
                        for (int it = 0; it < 16; ++it) {
                            int idx = it * 64 + lane;
                            dsth[idx] = cvt4_(wf[idx]);
                        }
                        if (lane == 0) p.gacc[rg] = p.b_ih_hp[rg] + p.b_hh_hp[rg];
                    } else {
                        const Half8* ww = (const Half8*)(p.hW_hh_hp + (size_t)rg * H_HP);
                        const float4* xx = (const float4*)p.c_hp;
                        float acc = 0.0f;
#pragma unroll
                        for (int it = 0; it < 8; ++it) {
                            int idx = it * 64 + lane;
                            acc += dot8h_(ww[idx], xx[2 * idx], xx[2 * idx + 1]);
                        }
                        acc = waveReduceSum(acc);
                        if (lane == 0) p.gacc[rg] = acc + p.b_ih_hp[rg] + p.b_hh_hp[rg];
                    }
                } else {
                    // logits_hp(t-1) = W_out_hp[ro]·h_hp(t-1) + b  (t>=1 only)
                    const int ro = r - 26624;
                    float acc = 0.0f;
                    const float4* xx = (const float4*)p.h_hp;
                    if (t == 1) {
                        const float4* wf = (const float4*)(p.W_out_hp + (size_t)ro * H_HP);
                        Half4* dsth = (Half4*)(p.hW_out_hp + (size_t)ro * H_HP);
#pragma unroll
                        for (int it = 0; it < 16; ++it) {
                            int idx = it * 64 + lane;
                            float4 w = wf[idx];
                            dsth[idx] = cvt4_(w);
                            acc += dot4_(w, xx[idx]);
                        }
                    } else {
                        const Half8* ww = (const Half8*)(p.hW_out_hp + (size_t)ro * H_HP);
#pragma unroll
                        for (int it = 0; it < 8; ++it) {
                            int idx = it * 64 + lane;
                            acc += dot8h_(ww[idx], xx[2 * idx], xx[2 * idx + 1]);
                        }
                    }
                    acc = waveReduceSum(acc);
                    if (lane == 0) p.logits_hp[ro] = acc + p.b_out_hp[ro];
                }
            }
        }
        grid.sync();

        // ---------------- P2: arch pointwise + W_out_a GEMV (16 blocks) ----
        if (blockIdx.x < 16) {
            float* h_s = sbuf;
            const float* cin = (t & 1) ? p.c_a1 : p.c_a0;
            float* cout = (t & 1) ? p.c_a0 : p.c_a1;
#pragma unroll
            for (int k = 0; k < 8; ++k) {
                int e = tid + k * 256;
                float gi = p.gates_a[e], gf = p.gates_a[H_A + e];
                float gg = p.gates_a[2 * H_A + e], go = p.gates_a[3 * H_A + e];
                float ci = (t == 0) ? 0.0f : cin[e];
                float c = fsig_(gf) * ci + fsig_(gi) * ftanh_(gg);
                float h = fsig_(go) * ftanh_(c);
                h_s[e] = h;
                if (blockIdx.x == 0) { cout[e] = c; p.h_a[e] = h; }
            }
            __syncthreads();
            const float4* h4 = (const float4*)h_s;
            int row = (blockIdx.x << 4) | (wv << 2);
            for (int j = 0; j < 4; ++j, ++row) {
                float acc = 0.0f;
                if (t == 0) {
                    const float4* wf = (const float4*)(p.W_out_a + (size_t)row * H_A);
                    Half4* dsth = (Half4*)(p.hW_out_a + (size_t)row * H_A);
#pragma unroll
                    for (int it = 0; it < 8; ++it) {
                        int idx = it * 64 + lane;
                        float4 w = wf[idx];
                        dsth[idx] = cvt4_(w);
                        acc += dot4_(w, h4[idx]);
                    }
                } else {
                    const Half8* ww = (const Half8*)(p.hW_out_a + (size_t)row * H_A);
#pragma unroll
                    for (int it = 0; it < 4; ++it) {
                        int idx = it * 64 + lane;
                        acc += dot8h_(ww[idx], h4[2 * idx], h4[2 * idx + 1]);
                    }
                }
                acc = waveReduceSum(acc);
                if (lane == 0) p.logits_a[row] = acc + p.b_out_a[row];
            }
        }
        grid.sync();

        // ---- P3: dual softmax (block-redundant) + W_ih_hp GEMV + hp LSTM --
        {
            float* p_all = sbuf;        // 512
            float* red   = sbuf + 512;  // 8
            float la = p.logits_a[tid];
            float lh = (t == 0) ? 0.0f : p.logits_hp[tid];  // softmax(0)=1/256 exact
            float ma = la, mh = lh;
#pragma unroll
            for (int off = 32; off > 0; off >>= 1) {
                ma = fmaxf(ma, __shfl_xor(ma, off, 64));
                mh = fmaxf(mh, __shfl_xor(mh, off, 64));
            }
            if (lane == 0) { red[wv] = ma; red[4 + wv] = mh; }
            __syncthreads();
            ma = fmaxf(fmaxf(red[0], red[1]), fmaxf(red[2], red[3]));
            mh = fmaxf(fmaxf(red[4], red[5]), fmaxf(red[6], red[7]));
            __syncthreads();
            float ea = __expf(la - ma), eh = __expf(lh - mh);
            float sa = waveReduceSum(ea), sh = waveReduceSum(eh);
            if (lane == 0) { red[wv] = sa; red[4 + wv] = sh; }
            __syncthreads();
            sa = red[0] + red[1] + red[2] + red[3];
            sh = red[4] + red[5] + red[6] + red[7];
            float pa = ea / sa, ph = eh / sh;
            p_all[tid] = pa;
            p_all[256 + tid] = ph;
            if (blockIdx.x == 0) {
                p.a_vec[tid] = pa;
                p.out[(size_t)t * 256 + tid] = pa;                          // out_a[t]
                if (t > 0) p.out[3072 + (size_t)(t - 1) * 256 + tid] = ph;  // out_hp[t-1]
            }
            __syncthreads();
            float4 xa = ((const float4*)p_all)[2 * lane];
            float4 xb = ((const float4*)p_all)[2 * lane + 1];
            for (int e = waveId; e < H_HP; e += nw) {
                float s0, s1, s2, s3;
                if (t == 0) {
                    auto rowdot_cvt = [&](int r) -> float {
                        const float4* wf = (const float4*)(p.W_ih_hp + (size_t)r * 512);
                        float4 u = wf[2 * lane], v = wf[2 * lane + 1];
                        ((Half8*)(p.hW_ih_hp + (size_t)r * 512))[lane] = cvt8_(u, v);
                        return dot4_(u, xa) + dot4_(v, xb);
                    };
                    s0 = rowdot_cvt(e);
                    s1 = rowdot_cvt(4096 + e);
                    s2 = rowdot_cvt(8192 + e);
                    s3 = rowdot_cvt(12288 + e);
                } else {
                    Half8 w0 = ((const Half8*)(p.hW_ih_hp + (size_t)e * 512))[lane];
                    Half8 w1 = ((const Half8*)(p.hW_ih_hp + (size_t)(4096 + e) * 512))[lane];
                    Half8 w2 = ((const Half8*)(p.hW_ih_hp + (size_t)(8192 + e) * 512))[lane];
                    Half8 w3 = ((const Half8*)(p.hW_ih_hp + (size_t)(12288 + e) * 512))[lane];
                    s0 = dot8h_(w0, xa, xb);
                    s1 = dot8h_(w1, xa, xb);
                    s2 = dot8h_(w2, xa, xb);
                    s3 = dot8h_(w3, xa, xb);
                }
                waveReduce4(s0, s1, s2, s3);
                if (lane == 0) {
                    float gi = s0 + p.gacc[e];
                    float gf = s1 + p.gacc[4096 + e];
                    float gg = s2 + p.gacc[8192 + e];
                    float go = s3 + p.gacc[12288 + e];
                    float prev = (e < H_A) ? p.h_a[e] : p.h_sum[e - H_A];
                    float c = fsig_(gf) * prev + fsig_(gi) * ftanh_(gg);
                    float h = fsig_(go) * ftanh_(c);
                    p.c_hp[e] = c;
                    p.h_hp[e] = h;
                }
            }
        }
        grid.sync();
    }

    // ---- epilogue: logits_hp(11) then softmax -> out_hp[11] ----
    if (blockIdx.x < 16) {
        int row = (blockIdx.x << 4) | (wv << 2);
        const float4* xx = (const float4*)p.h_hp;
        for (int j = 0; j < 4; ++j, ++row) {
            const Half8* ww = (const Half8*)(p.hW_out_hp + (size_t)row * H_HP);
            float acc = 0.0f;
#pragma unroll
            for (int it = 0; it < 8; ++it) {
                int idx = it * 64 + lane;
                acc += dot8h_(ww[idx], xx[2 * idx], xx[2 * idx + 1]);
            }
            acc = waveReduceSum(acc);
            if (lane == 0) p.logits_hp[row] = acc + p.b_out_hp[row];
        }
    }
    grid.sync();
    if (blockIdx.x == 0) {
        float* red = sbuf + 512;
        float v = p.logits_hp[tid];
        float m = v;
#pragma unroll
        for (int off = 32; off > 0; off >>= 1) m = fmaxf(m, __shfl_xor(m, off, 64));
        if (lane == 0) red[wv] = m;
        __syncthreads();
        m = fmaxf(fmaxf(red[0], red[1]), fmaxf(red[2], red[3]));
        __syncthreads();
        float e = __expf(v - m);
        float s = waveReduceSum(e);
        if (lane == 0) red[wv] = s;
        __syncthreads();
        s = red[0] + red[1] + red[2] + red[3];
        p.out[3072 + 11 * 256 + tid] = e / s;
    }
}

// ===========================================================================
// FALLBACK PATH — round-3 proven multi-kernel implementation (passed,
// 1137 us, absmax 3.05e-5). Used only if the cooperative launch is rejected.
// ===========================================================================
__global__ void k_init(const float* __restrict__ x_a, const float* __restrict__ x_hp,
                       float* __restrict__ h_a, float* __restrict__ c_a0,
                       float* __restrict__ h_hp, float* __restrict__ c_hp,
                       float* __restrict__ a_vec, float* __restrict__ logits_hp)
{
    int i = blockIdx.x * 256 + threadIdx.x;
    if (i < H_A)  { h_a[i] = x_a[i];  c_a0[i] = 0.0f; }
    if (i < H_HP) { h_hp[i] = x_hp[i]; c_hp[i] = 0.0f; }
    if (i < 256)  { a_vec[i] = 1.0f / 256.0f; logits_hp[i] = 0.0f; }
}

__global__ __launch_bounds__(256) void k_f2h_batched(
    const float* __restrict__ W_ih_a,  __half* __restrict__ hW_ih_a,
    const float* __restrict__ W_hh_a,  __half* __restrict__ hW_hh_a,
    const float* __restrict__ W_sum,   __half* __restrict__ hW_sum,
    const float* __restrict__ W_ih_hp, __half* __restrict__ hW_ih_hp,
    const float* __restrict__ W_out_a, __half* __restrict__ hW_out_a,
    const float* __restrict__ W_out_hp,__half* __restrict__ hW_out_hp)
{
    int i = blockIdx.x * 256 + threadIdx.x;
    const float* src; __half* dst; int base;
    if      (i < 262144)  { src = W_ih_a;   dst = hW_ih_a;   base = 0; }
    else if (i < 2359296) { src = W_hh_a;   dst = hW_hh_a;   base = 262144; }
    else if (i < 3407872) { src = W_sum;    dst = hW_sum;    base = 2359296; }
    else if (i < 4456448) { src = W_ih_hp;  dst = hW_ih_hp;  base = 3407872; }
    else if (i < 4521984) { src = W_out_a;  dst = hW_out_a;  base = 4456448; }
    else if (i < 4653056) { src = W_out_hp; dst = hW_out_hp; base = 4521984; }
    else return;
    int j = i - base;
    float4 a = ((const float4*)src)[2 * j];
    float4 b = ((const float4*)src)[2 * j + 1];
    ((Half8*)dst)[j] = cvt8_(a, b);
}

__global__ __launch_bounds__(256) void kA_fused_gemv(
    const __half* __restrict__ hW_ih_a, const __half* __restrict__ hW_hh_a,
    const float* __restrict__ b_ih_a, const float* __restrict__ b_hh_a,
    const __half* __restrict__ hW_sum,  const float* __restrict__ b_sum,
    __half* __restrict__ hW_hh_hp, const float* __restrict__ W_hh_hp_f32,
    const float* __restrict__ b_ih_hp, const float* __restrict__ b_hh_hp,
    const float* __restrict__ a_vec,  const float* __restrict__ h_a,
    const float* __restrict__ h_hp,   const float* __restrict__ c_hp,
    float* __restrict__ gates_a, float* __restrict__ h_sum_o,
    float* __restrict__ gacc_hp, int step0)
{
    const int lane = threadIdx.x & 63;
    const int wave = (blockIdx.x << 2) | (threadIdx.x >> 6);

    if (wave < 8192) {
        const int r = wave;
        const __half2* wp = (const __half2*)(hW_ih_a + (size_t)r * 256);
        __half2 w0h = wp[2 * lane], w1h = wp[2 * lane + 1];
        float4 x = ((const float4*)a_vec)[lane];
        float2 w0 = __half22float2(w0h), w1 = __half22float2(w1h);
        float acc = w0.x * x.x + w0.y * x.y + w1.x * x.z + w1.y * x.w;
        const Half8* wh = (const Half8*)(hW_hh_a + (size_t)r * H_A);
        const float4* xh = (const float4*)h_a;
#pragma unroll
        for (int it = 0; it < 4; ++it) {
            int idx = it * 64 + lane;
            acc += dot8h_(wh[idx], xh[2 * idx], xh[2 * idx + 1]);
        }
        acc = waveReduceSum(acc);
        if (lane == 0) gates_a[r] = acc + b_ih_a[r] + b_hh_a[r];
    } else if (wave < 10240) {
        const int r = wave - 8192;
        const Half8* ww = (const Half8*)(hW_sum + (size_t)r * H_HP);
        const float4* xx = (const float4*)h_hp;
        float acc = 0.0f;
#pragma unroll
        for (int it = 0; it < 8; ++it) {
            int idx = it * 64 + lane;
            acc += dot8h_(ww[idx], xx[2 * idx], xx[2 * idx + 1]);
        }
        acc = waveReduceSum(acc);
        if (lane == 0) h_sum_o[r] = fmaxf(acc + b_sum[r], 0.0f);
    } else {
        const int r = wave - 10240;
        if (step0) {
            const float4* src = (const float4*)(W_hh_hp_f32 + (size_t)r * H_HP);
            Half8* dst = (Half8*)(hW_hh_hp + (size_t)r * H_HP);
#pragma unroll
            for (int it = 0; it < 8; ++it) {
                int idx = it * 64 + lane;
                dst[idx] = cvt8_(src[2 * idx], src[2 * idx + 1]);
            }
            if (lane == 0) gacc_hp[r] = b_ih_hp[r] + b_hh_hp[r];
        } else {
            const Half8* ww = (const Half8*)(hW_hh_hp + (size_t)r * H_HP);
            const float4* xx = (const float4*)c_hp;
            float acc = 0.0f;
#pragma unroll
            for (int it = 0; it < 8; ++it) {
                int idx = it * 64 + lane;
                acc += dot8h_(ww[idx], xx[2 * idx], xx[2 * idx + 1]);
            }
            acc = waveReduceSum(acc);
            if (lane == 0) gacc_hp[r] = acc + b_ih_hp[r] + b_hh_hp[r];
        }
    }
}

__global__ __launch_bounds__(256) void kB_arch(
    const float* __restrict__ gates_a, const float* __restrict__ c_in,
    float* __restrict__ c_out, float* __restrict__ h_a_g,
    const __half* __restrict__ hW_out_a, const float* __restrict__ b_out_a,
    float* __restrict__ logits_a)
{
    __shared__ float h_s[H_A];
    const int t = threadIdx.x;
#pragma unroll
    for (int k = 0; k < 8; ++k) {
        int e = t + k * 256;
        float gi = gates_a[e];
        float gf = gates_a[H_A + e];
        float gg = gates_a[2 * H_A + e];
        float go = gates_a[3 * H_A + e];
        float c_new = fsig_(gf) * c_in[e] + fsig_(gi) * ftanh_(gg);
        float h = fsig_(go) * ftanh_(c_new);
        h_s[e] = h;
        if (blockIdx.x == 0) { c_out[e] = c_new; h_a_g[e] = h; }
    }
    __syncthreads();
    const int lane = t & 63;
    const int r = (blockIdx.x << 2) | (t >> 6);
    const Half8* w8 = (const Half8*)(hW_out_a + (size_t)r * H_A);
    const float4* h4 = (const float4*)h_s;
    float acc = 0.0f;
#pragma unroll
    for (int it = 0; it < 4; ++it) {
        int idx = it * 64 + lane;
        acc += dot8h_(w8[idx], h4[2 * idx], h4[2 * idx + 1]);
    }
    acc = waveReduceSum(acc);
    if (lane == 0) logits_a[r] = acc + b_out_a[r];
}

__global__ __launch_bounds__(256) void kC_softmax_ih(
    const float* __restrict__ logits_a, const float* __restrict__ logits_hp,
    const __half* __restrict__ hW_ih_hp, float* __restrict__ gacc_hp,
    float* __restrict__ a_vec_g, float* __restrict__ out_a,
    float* __restrict__ out_hp)
{
    __shared__ float p_all[512];
    __shared__ float red[8];
    const int t = threadIdx.x, lane = t & 63, wv = t >> 6;
    float la = logits_a[t], lh = logits_hp[t];
    float ma = la, mh = lh;
#pragma unroll
    for (int off = 32; off > 0; off >>= 1) {
        ma = fmaxf(ma, __shfl_xor(ma, off, 64));
        mh = fmaxf(mh, __shfl_xor(mh, off, 64));
    }
    if (lane == 0) { red[wv] = ma; red[4 + wv] = mh; }
    __syncthreads();
    ma = fmaxf(fmaxf(red[0], red[1]), fmaxf(red[2], red[3]));
    mh = fmaxf(fmaxf(red[4], red[5]), fmaxf(red[6], red[7]));
    __syncthreads();
    float ea = __expf(la - ma), eh = __expf(lh - mh);
    float sa = waveReduceSum(ea), sh = waveReduceSum(eh);
    if (lane == 0) { red[wv] = sa; red[4 + wv] = sh; }
    __syncthreads();
    sa = red[0] + red[1] + red[2] + red[3];
    sh = red[4] + red[5] + red[6] + red[7];
    float pa = ea / sa, ph = eh / sh;
    p_all[t] = pa;
    p_all[256 + t] = ph;
    if (blockIdx.x == 0) {
        a_vec_g[t] = pa;
        out_a[t] = pa;
        out_hp[t] = ph;
    }
    __syncthreads();
    const float4* x4 = (const float4*)p_all;
    float4 xa = x4[2 * lane], xb = x4[2 * lane + 1];
    const int gw = (blockIdx.x << 2) | wv;
#pragma unroll
    for (int rr = 0; rr < 4; ++rr) {
        int r = (gw << 2) | rr;
        Half8 w = ((const Half8*)(hW_ih_hp + (size_t)r * 512))[lane];
        float acc = dot8h_(w, xa, xb);
        acc = waveReduceSum(acc);
        if (lane == 0) gacc_hp[r] += acc;
    }
}

__global__ __launch_bounds__(256) void kD_hp(
    const float* __restrict__ gacc_hp, const float* __restrict__ h_a,
    const float* __restrict__ h_sum, float* __restrict__ c_hp_g,
    float* __restrict__ h_hp_g,
    const __half* __restrict__ hW_out_hp, const float* __restrict__ b_out_hp,
    float* __restrict__ logits_hp)
{
    __shared__ float h_s[H_HP];
    const int t = threadIdx.x;
#pragma unroll
    for (int k = 0; k < 16; ++k) {
        int e = t + k * 256;
        float gi = gacc_hp[e];
        float gf = gacc_hp[H_HP + e];
        float gg = gacc_hp[2 * H_HP + e];
        float go = gacc_hp[3 * H_HP + e];
        float prev = (e < H_A) ? h_a[e] : h_sum[e - H_A];
        float c = fsig_(gf) * prev + fsig_(gi) * ftanh_(gg);
        float h = fsig_(go) * ftanh_(c);
        h_s[e] = h;
        if (blockIdx.x == 0) { c_hp_g[e] = c; h_hp_g[e] = h; }
    }
    __syncthreads();
    const int lane = t & 63;
    const int r = (blockIdx.x << 2) | (t >> 6);
    const Half8* w8 = (const Half8*)(hW_out_hp + (size_t)r * H_HP);
    const float4* x4 = (const float4*)h_s;
    float acc = 0.0f;
#pragma unroll
    for (int it = 0; it < 8; ++it) {
        int idx = it * 64 + lane;
        acc += dot8h_(w8[idx], x4[2 * idx], x4[2 * idx + 1]);
    }
    acc = waveReduceSum(acc);
    if (lane == 0) logits_hp[r] = acc + b_out_hp[r];
}

__global__ __launch_bounds__(256) void k_softmax_tail(
    const float* __restrict__ logits_hp, float* __restrict__ outp)
{
    __shared__ float red[4];
    const int t = threadIdx.x, lane = t & 63, wv = t >> 6;
    float v = logits_hp[t];
    float m = v;
#pragma unroll
    for (int off = 32; off > 0; off >>= 1) m = fmaxf(m, __shfl_xor(m, off, 64));
    if (lane == 0) red[wv] = m;
    __syncthreads();
    m = fmaxf(fmaxf(red[0], red[1]), fmaxf(red[2], red[3]));
    __syncthreads();
    float e = __expf(v - m);
    float s = waveReduceSum(e);
    if (lane == 0) red[wv] = s;
    __syncthreads();
    s = red[0] + red[1] + red[2] + red[3];
    outp[t] = e / s;
}

// ---------------------------------------------------------------------------

extern "C" void kernel_launch(void* const* d_in, const int* in_sizes, int n_in,
                              void* d_out, int out_size, void* d_ws, size_t ws_size,
                              hipStream_t stream)
{
    Params p;
    p.x_a      = (const float*)d_in[0];
    p.x_hp     = (const float*)d_in[1];
    p.W_ih_a   = (const float*)d_in[2];
    p.W_hh_a   = (const float*)d_in[3];
    p.b_ih_a   = (const float*)d_in[4];
    p.b_hh_a   = (const float*)d_in[5];
    p.W_out_a  = (const float*)d_in[6];
    p.b_out_a  = (const float*)d_in[7];
    p.W_sum    = (const float*)d_in[8];
    p.b_sum    = (const float*)d_in[9];
    p.W_ih_hp  = (const float*)d_in[10];
    p.W_hh_hp  = (const float*)d_in[11];
    p.b_ih_hp  = (const float*)d_in[12];
    p.b_hh_hp  = (const float*)d_in[13];
    p.W_out_hp = (const float*)d_in[14];
    p.b_out_hp = (const float*)d_in[15];

    // ws layout: fp16 weights first (16B aligned), then fp32 state
    p.hW_ih_a   = (__half*)d_ws;                     //  2,097,152 halves
    p.hW_hh_a   = p.hW_ih_a   + 2097152;             // 16,777,216
    p.hW_sum    = p.hW_hh_a   + 16777216;            //  8,388,608
    p.hW_ih_hp  = p.hW_sum    + 8388608;             //  8,388,608
    p.hW_hh_hp  = p.hW_ih_hp  + 8388608;             // 67,108,864
    p.hW_out_a  = p.hW_hh_hp  + 67108864;            //    524,288
    p.hW_out_hp = p.hW_out_a  + 524288;              //  1,048,576
    float* ws = (float*)(p.hW_out_hp + 1048576);

    p.gates_a   = ws;           // 8192
    p.h_sum     = ws + 8192;    // 2048
    p.gacc      = ws + 10240;   // 16384
    p.h_a       = ws + 26624;   // 2048
    p.c_a0      = ws + 28672;   // 2048
    p.c_a1      = ws + 30720;   // 2048
    p.h_hp      = ws + 32768;   // 4096
    p.c_hp      = ws + 36864;   // 4096
    p.logits_a  = ws + 40960;   // 256
    p.logits_hp = ws + 41216;   // 256
    p.a_vec     = ws + 41472;   // 256
    float* dummy = ws + 41728;  // 256 (fallback step-0 a_hp out slot)
    p.out       = (float*)d_out;

    // --- cooperative path: runtime-sized grid, checked launch -------------
    int blocksPerCU = 0;
    hipError_t qerr = hipOccupancyMaxActiveBlocksPerMultiprocessor(
        &blocksPerCU, (const void*)decoder_persistent, 256, 0);
    if (qerr == hipSuccess && blocksPerCU >= 1) {
        int grid = blocksPerCU * 256;     // 256 CUs on MI355X
        if (grid > 1024) grid = 1024;
        void* kargs[] = { (void*)&p };
        hipError_t lerr = hipLaunchCooperativeKernel(
            (const void*)decoder_persistent, dim3(grid), dim3(256), kargs, 0, stream);
        if (lerr == hipSuccess) return;
    }

    // --- fallback: proven multi-kernel path -------------------------------
    k_init<<<16, 256, 0, stream>>>(p.x_a, p.x_hp, p.h_a, p.c_a0, p.h_hp, p.c_hp,
                                   p.a_vec, p.logits_hp);
    k_f2h_batched<<<18176, 256, 0, stream>>>(
        p.W_ih_a, p.hW_ih_a, p.W_hh_a, p.hW_hh_a, p.W_sum, p.hW_sum,
        p.W_ih_hp, p.hW_ih_hp, p.W_out_a, p.hW_out_a, p.W_out_hp, p.hW_out_hp);

    float* c_a[2] = { p.c_a0, p.c_a1 };
    float* out = p.out;
    for (int t = 0; t < DEPTH; ++t) {
        kA_fused_gemv<<<6656, 256, 0, stream>>>(
            p.hW_ih_a, p.hW_hh_a, p.b_ih_a, p.b_hh_a, p.hW_sum, p.b_sum,
            p.hW_hh_hp, p.W_hh_hp, p.b_ih_hp, p.b_hh_hp,
            p.a_vec, p.h_a, p.h_hp, p.c_hp,
            p.gates_a, p.h_sum, p.gacc, (t == 0) ? 1 : 0);

        kB_arch<<<64, 256, 0, stream>>>(p.gates_a, c_a[t & 1], c_a[(t + 1) & 1],
                                        p.h_a, p.hW_out_a, p.b_out_a, p.logits_a);

        kC_softmax_ih<<<1024, 256, 0, stream>>>(
            p.logits_a, p.logits_hp, p.hW_ih_hp, p.gacc,
            p.a_vec, out + (size_t)t * 256,
            (t == 0) ? dummy : out + 3072 + (size_t)(t - 1) * 256);

        kD_hp<<<64, 256, 0, stream>>>(p.gacc, p.h_a, p.h_sum, p.c_hp, p.h_hp,
                                      p.hW_out_hp, p.b_out_hp, p.logits_hp);
    }

    k_softmax_tail<<<1, 256, 0, stream>>>(p.logits_hp, out + 3072 + 11 * 256);
}

// Round 6
// 982.644 us; speedup vs baseline: 1.1597x; 1.1597x over previous
//
#include <hip/hip_runtime.h>
#include <hip/hip_fp16.h>

#define H_A   2048
#define H_HP  4096
#define DEPTH 12

struct Half8 { __half2 a, b, c, d; };   // 16 B
struct Half4 { __half2 a, b; };         // 8 B

__device__ __forceinline__ float fsig_(float x) { return 1.0f / (1.0f + __expf(-x)); }
__device__ __forceinline__ float ftanh_(float x) {
    return 1.0f - 2.0f / (__expf(2.0f * x) + 1.0f);
}
__device__ __forceinline__ float dot4_(float4 a, float4 b) {
    return a.x * b.x + a.y * b.y + a.z * b.z + a.w * b.w;
}
__device__ __forceinline__ float dot8h_(Half8 w, float4 x0, float4 x1) {
    float2 wa = __half22float2(w.a), wb = __half22float2(w.b);
    float2 wc = __half22float2(w.c), wd = __half22float2(w.d);
    return wa.x * x0.x + wa.y * x0.y + wb.x * x0.z + wb.y * x0.w +
           wc.x * x1.x + wc.y * x1.y + wd.x * x1.z + wd.y * x1.w;
}
__device__ __forceinline__ Half4 cvt4_(float4 a) {
    Half4 h;
    h.a = __floats2half2_rn(a.x, a.y);
    h.b = __floats2half2_rn(a.z, a.w);
    return h;
}
__device__ __forceinline__ Half8 cvt8_(float4 a, float4 b) {
    Half8 h;
    h.a = __floats2half2_rn(a.x, a.y);
    h.b = __floats2half2_rn(a.z, a.w);
    h.c = __floats2half2_rn(b.x, b.y);
    h.d = __floats2half2_rn(b.z, b.w);
    return h;
}
__device__ __forceinline__ float waveReduceSum(float v) {
#pragma unroll
    for (int off = 32; off > 0; off >>= 1) v += __shfl_xor(v, off, 64);
    return v;
}
__device__ __forceinline__ void waveReduce4(float& a0, float& a1, float& a2, float& a3) {
#pragma unroll
    for (int off = 32; off > 0; off >>= 1) {
        a0 += __shfl_xor(a0, off, 64);
        a1 += __shfl_xor(a1, off, 64);
        a2 += __shfl_xor(a2, off, 64);
        a3 += __shfl_xor(a3, off, 64);
    }
}

struct Params {
    const float *x_a, *x_hp;
    const float *W_ih_a, *W_hh_a, *b_ih_a, *b_hh_a;
    const float *W_out_a, *b_out_a, *W_sum, *b_sum;
    const float *W_ih_hp, *W_hh_hp, *b_ih_hp, *b_hh_hp, *W_out_hp, *b_out_hp;
    __half *hW_ih_a, *hW_hh_a, *hW_sum, *hW_ih_hp, *hW_hh_hp, *hW_out_a, *hW_out_hp;
    float *gates_a, *h_sum, *gacc, *h_a, *c_a0, *c_a1, *h_hp, *c_hp;
    float *logits_a, *logits_hp, *a_vec, *out;
};

// ===========================================================================
// kA: all big GEMVs, one wave per row (6720 blocks x 256 = 26880 waves).
//   waves [0,8192):      gates_a[r]  = W_ih_a[r]·a(t-1) + W_hh_a[r]·h_a(t-1) + b
//   waves [8192,10240):  h_sum[r]    = relu(W_sum[r]·h_hp(t-1) + b_sum[r])
//   waves [10240,26624): gacc[r]     = W_hh_hp[r]·c_hp(t-1) + b_ih_hp + b_hh_hp
//   waves [26624,26880): logits_hp(t-1) = W_out_hp[r]·h_hp(t-1) + b  (t>=1)
// t==0: reads fp32 sources (exact initial state: a=1/256, h=x, c=0) while
// writing the fp16 copy used by t>=1. t==1: same for W_out_hp.
// ===========================================================================
__global__ __launch_bounds__(256) void kA(Params p, int t)
{
    const int lane = threadIdx.x & 63;
    const int wave = (blockIdx.x << 2) | (threadIdx.x >> 6);

    if (wave < 8192) {
        const int r = wave;
        float acc;
        if (t == 0) {
            float4 wf = ((const float4*)(p.W_ih_a + (size_t)r * 256))[lane];
            ((Half4*)(p.hW_ih_a + (size_t)r * 256))[lane] = cvt4_(wf);
            acc = (wf.x + wf.y + wf.z + wf.w) * (1.0f / 256.0f);
            const float4* whf = (const float4*)(p.W_hh_a + (size_t)r * H_A);
            const float4* xh = (const float4*)p.x_a;
            Half4* dsth = (Half4*)(p.hW_hh_a + (size_t)r * H_A);
#pragma unroll
            for (int it = 0; it < 8; ++it) {
                int idx = it * 64 + lane;
                float4 w = whf[idx];
                dsth[idx] = cvt4_(w);
                acc += dot4_(w, xh[idx]);
            }
        } else {
            Half4 w = ((const Half4*)(p.hW_ih_a + (size_t)r * 256))[lane];
            float4 x = ((const float4*)p.a_vec)[lane];
            float2 w0 = __half22float2(w.a), w1 = __half22float2(w.b);
            acc = w0.x * x.x + w0.y * x.y + w1.x * x.z + w1.y * x.w;
            const Half8* wh = (const Half8*)(p.hW_hh_a + (size_t)r * H_A);
            const float4* xh = (const float4*)p.h_a;
#pragma unroll
            for (int it = 0; it < 4; ++it) {
                int idx = it * 64 + lane;
                acc += dot8h_(wh[idx], xh[2 * idx], xh[2 * idx + 1]);
            }
        }
        acc = waveReduceSum(acc);
        if (lane == 0) p.gates_a[r] = acc + p.b_ih_a[r] + p.b_hh_a[r];
    } else if (wave < 10240) {
        const int rr = wave - 8192;
        float acc = 0.0f;
        if (t == 0) {
            const float4* wf = (const float4*)(p.W_sum + (size_t)rr * H_HP);
            const float4* xx = (const float4*)p.x_hp;
            Half4* dsth = (Half4*)(p.hW_sum + (size_t)rr * H_HP);
#pragma unroll
            for (int it = 0; it < 16; ++it) {
                int idx = it * 64 + lane;
                float4 w = wf[idx];
                dsth[idx] = cvt4_(w);
                acc += dot4_(w, xx[idx]);
            }
        } else {
            const Half8* ww = (const Half8*)(p.hW_sum + (size_t)rr * H_HP);
            const float4* xx = (const float4*)p.h_hp;
#pragma unroll
            for (int it = 0; it < 8; ++it) {
                int idx = it * 64 + lane;
                acc += dot8h_(ww[idx], xx[2 * idx], xx[2 * idx + 1]);
            }
        }
        acc = waveReduceSum(acc);
        if (lane == 0) p.h_sum[rr] = fmaxf(acc + p.b_sum[rr], 0.0f);
    } else if (wave < 26624) {
        const int rg = wave - 10240;
        if (t == 0) {
            // c_hp(-1)=0 exactly: convert row, write bias-only gacc
            const float4* wf = (const float4*)(p.W_hh_hp + (size_t)rg * H_HP);
            Half4* dsth = (Half4*)(p.hW_hh_hp + (size_t)rg * H_HP);
#pragma unroll
            for (int it = 0; it < 16; ++it) {
                int idx = it * 64 + lane;
                dsth[idx] = cvt4_(wf[idx]);
            }
            if (lane == 0) p.gacc[rg] = p.b_ih_hp[rg] + p.b_hh_hp[rg];
        } else {
            const Half8* ww = (const Half8*)(p.hW_hh_hp + (size_t)rg * H_HP);
            const float4* xx = (const float4*)p.c_hp;
            float acc = 0.0f;
#pragma unroll
            for (int it = 0; it < 8; ++it) {
                int idx = it * 64 + lane;
                acc += dot8h_(ww[idx], xx[2 * idx], xx[2 * idx + 1]);
            }
            acc = waveReduceSum(acc);
            if (lane == 0) p.gacc[rg] = acc + p.b_ih_hp[rg] + p.b_hh_hp[rg];
        }
    } else {
        if (t == 0) return;                 // no h_hp yet at t==0
        const int ro = wave - 26624;
        float acc = 0.0f;
        const float4* xx = (const float4*)p.h_hp;
        if (t == 1) {
            const float4* wf = (const float4*)(p.W_out_hp + (size_t)ro * H_HP);
            Half4* dsth = (Half4*)(p.hW_out_hp + (size_t)ro * H_HP);
#pragma unroll
            for (int it = 0; it < 16; ++it) {
                int idx = it * 64 + lane;
                float4 w = wf[idx];
                dsth[idx] = cvt4_(w);
                acc += dot4_(w, xx[idx]);
            }
        } else {
            const Half8* ww = (const Half8*)(p.hW_out_hp + (size_t)ro * H_HP);
#pragma unroll
            for (int it = 0; it < 8; ++it) {
                int idx = it * 64 + lane;
                acc += dot8h_(ww[idx], xx[2 * idx], xx[2 * idx + 1]);
            }
        }
        acc = waveReduceSum(acc);
        if (lane == 0) p.logits_hp[ro] = acc + p.b_out_hp[ro];
    }
}

// ===========================================================================
// kB: arch pointwise LSTM (redundant per block, h into LDS) + W_out_a GEMV.
// 64 blocks x 256 threads -> 256 rows (one per wave). Block 0 writes state.
// t==0: c_a = 0 exactly; converts W_out_a to fp16 while computing from fp32.
// ===========================================================================
__global__ __launch_bounds__(256) void kB(Params p, int t)
{
    __shared__ float h_s[H_A];
    const int tid = threadIdx.x;
    const float* cin = (t & 1) ? p.c_a1 : p.c_a0;
    float* cout = (t & 1) ? p.c_a0 : p.c_a1;
#pragma unroll
    for (int k = 0; k < 8; ++k) {
        int e = tid + k * 256;
        float gi = p.gates_a[e], gf = p.gates_a[H_A + e];
        float gg = p.gates_a[2 * H_A + e], go = p.gates_a[3 * H_A + e];
        float ci = (t == 0) ? 0.0f : cin[e];
        float c = fsig_(gf) * ci + fsig_(gi) * ftanh_(gg);
        float h = fsig_(go) * ftanh_(c);
        h_s[e] = h;
        if (blockIdx.x == 0) { cout[e] = c; p.h_a[e] = h; }
    }
    __syncthreads();
    const int lane = tid & 63;
    const int r = (blockIdx.x << 2) | (tid >> 6);
    const float4* h4 = (const float4*)h_s;
    float acc = 0.0f;
    if (t == 0) {
        const float4* wf = (const float4*)(p.W_out_a + (size_t)r * H_A);
        Half4* dsth = (Half4*)(p.hW_out_a + (size_t)r * H_A);
#pragma unroll
        for (int it = 0; it < 8; ++it) {
            int idx = it * 64 + lane;
            float4 w = wf[idx];
            dsth[idx] = cvt4_(w);
            acc += dot4_(w, h4[idx]);
        }
    } else {
        const Half8* ww = (const Half8*)(p.hW_out_a + (size_t)r * H_A);
#pragma unroll
        for (int it = 0; it < 4; ++it) {
            int idx = it * 64 + lane;
            acc += dot8h_(ww[idx], h4[2 * idx], h4[2 * idx + 1]);
        }
    }
    acc = waveReduceSum(acc);
    if (lane == 0) p.logits_a[r] = acc + p.b_out_a[r];
}

// ===========================================================================
// kC: block-redundant dual softmax (a(t) from logits_a; a_hp(t-1) from
// logits_hp — t==0 uses logits 0 -> exactly 1/256) + W_ih_hp GEMV + hp
// pointwise LSTM (reference's swapped states: cell input = [h_a, h_sum]).
// 1024 blocks x 256 threads; wave w owns element e=w: loads rows e, 4096+e,
// 8192+e, 12288+e (i,f,g,o), reduces, lane0 computes the LSTM pointwise.
// Block 0 writes a_vec, out_a[t], out_hp[t-1].
// ===========================================================================
__global__ __launch_bounds__(256) void kC(Params p, int t)
{
    __shared__ float p_all[512];
    __shared__ float red[8];
    const int tid = threadIdx.x, lane = tid & 63, wv = tid >> 6;
    float la = p.logits_a[tid];
    float lh = (t == 0) ? 0.0f : p.logits_hp[tid];
    float ma = la, mh = lh;
#pragma unroll
    for (int off = 32; off > 0; off >>= 1) {
        ma = fmaxf(ma, __shfl_xor(ma, off, 64));
        mh = fmaxf(mh, __shfl_xor(mh, off, 64));
    }
    if (lane == 0) { red[wv] = ma; red[4 + wv] = mh; }
    __syncthreads();
    ma = fmaxf(fmaxf(red[0], red[1]), fmaxf(red[2], red[3]));
    mh = fmaxf(fmaxf(red[4], red[5]), fmaxf(red[6], red[7]));
    __syncthreads();
    float ea = __expf(la - ma), eh = __expf(lh - mh);
    float sa = waveReduceSum(ea), sh = waveReduceSum(eh);
    if (lane == 0) { red[wv] = sa; red[4 + wv] = sh; }
    __syncthreads();
    sa = red[0] + red[1] + red[2] + red[3];
    sh = red[4] + red[5] + red[6] + red[7];
    float pa = ea / sa, ph = eh / sh;
    p_all[tid] = pa;
    p_all[256 + tid] = ph;
    if (blockIdx.x == 0) {
        p.a_vec[tid] = pa;
        p.out[(size_t)t * 256 + tid] = pa;                          // out_a[t]
        if (t > 0) p.out[3072 + (size_t)(t - 1) * 256 + tid] = ph;  // out_hp[t-1]
    }
    __syncthreads();
    float4 xa = ((const float4*)p_all)[2 * lane];
    float4 xb = ((const float4*)p_all)[2 * lane + 1];
    const int e = (blockIdx.x << 2) | wv;   // 0..4095
    float s0, s1, s2, s3;
    if (t == 0) {
        auto rowdot_cvt = [&](int r) -> float {
            const float4* wf = (const float4*)(p.W_ih_hp + (size_t)r * 512);
            float4 u = wf[2 * lane], v = wf[2 * lane + 1];
            ((Half8*)(p.hW_ih_hp + (size_t)r * 512))[lane] = cvt8_(u, v);
            return dot4_(u, xa) + dot4_(v, xb);
        };
        s0 = rowdot_cvt(e);
        s1 = rowdot_cvt(4096 + e);
        s2 = rowdot_cvt(8192 + e);
        s3 = rowdot_cvt(12288 + e);
    } else {
        Half8 w0 = ((const Half8*)(p.hW_ih_hp + (size_t)e * 512))[lane];
        Half8 w1 = ((const Half8*)(p.hW_ih_hp + (size_t)(4096 + e) * 512))[lane];
        Half8 w2 = ((const Half8*)(p.hW_ih_hp + (size_t)(8192 + e) * 512))[lane];
        Half8 w3 = ((const Half8*)(p.hW_ih_hp + (size_t)(12288 + e) * 512))[lane];
        s0 = dot8h_(w0, xa, xb);
        s1 = dot8h_(w1, xa, xb);
        s2 = dot8h_(w2, xa, xb);
        s3 = dot8h_(w3, xa, xb);
    }
    waveReduce4(s0, s1, s2, s3);
    if (lane == 0) {
        float gi = s0 + p.gacc[e];
        float gf = s1 + p.gacc[4096 + e];
        float gg = s2 + p.gacc[8192 + e];
        float go = s3 + p.gacc[12288 + e];
        float prev = (e < H_A) ? p.h_a[e] : p.h_sum[e - H_A];
        float c = fsig_(gf) * prev + fsig_(gi) * ftanh_(gg);
        float h = fsig_(go) * ftanh_(c);
        p.c_hp[e] = c;
        p.h_hp[e] = h;
    }
}

// ===========================================================================
// tail: logits_hp(11) = W_out_hp·h_hp(11) (64 blocks), then softmax (1 block)
// ===========================================================================
__global__ __launch_bounds__(256) void kTail_gemv(Params p)
{
    const int lane = threadIdx.x & 63;
    const int r = (blockIdx.x << 2) | (threadIdx.x >> 6);
    const Half8* ww = (const Half8*)(p.hW_out_hp + (size_t)r * H_HP);
    const float4* xx = (const float4*)p.h_hp;
    float acc = 0.0f;
#pragma unroll
    for (int it = 0; it < 8; ++it) {
        int idx = it * 64 + lane;
        acc += dot8h_(ww[idx], xx[2 * idx], xx[2 * idx + 1]);
    }
    acc = waveReduceSum(acc);
    if (lane == 0) p.logits_hp[r] = acc + p.b_out_hp[r];
}

__global__ __launch_bounds__(256) void kTail_softmax(Params p)
{
    __shared__ float red[4];
    const int tid = threadIdx.x, lane = tid & 63, wv = tid >> 6;
    float v = p.logits_hp[tid];
    float m = v;
#pragma unroll
    for (int off = 32; off > 0; off >>= 1) m = fmaxf(m, __shfl_xor(m, off, 64));
    if (lane == 0) red[wv] = m;
    __syncthreads();
    m = fmaxf(fmaxf(red[0], red[1]), fmaxf(red[2], red[3]));
    __syncthreads();
    float e = __expf(v - m);
    float s = waveReduceSum(e);
    if (lane == 0) red[wv] = s;
    __syncthreads();
    s = red[0] + red[1] + red[2] + red[3];
    p.out[3072 + 11 * 256 + tid] = e / s;
}

// ---------------------------------------------------------------------------

extern "C" void kernel_launch(void* const* d_in, const int* in_sizes, int n_in,
                              void* d_out, int out_size, void* d_ws, size_t ws_size,
                              hipStream_t stream)
{
    Params p;
    p.x_a      = (const float*)d_in[0];
    p.x_hp     = (const float*)d_in[1];
    p.W_ih_a   = (const float*)d_in[2];
    p.W_hh_a   = (const float*)d_in[3];
    p.b_ih_a   = (const float*)d_in[4];
    p.b_hh_a   = (const float*)d_in[5];
    p.W_out_a  = (const float*)d_in[6];
    p.b_out_a  = (const float*)d_in[7];
    p.W_sum    = (const float*)d_in[8];
    p.b_sum    = (const float*)d_in[9];
    p.W_ih_hp  = (const float*)d_in[10];
    p.W_hh_hp  = (const float*)d_in[11];
    p.b_ih_hp  = (const float*)d_in[12];
    p.b_hh_hp  = (const float*)d_in[13];
    p.W_out_hp = (const float*)d_in[14];
    p.b_out_hp = (const float*)d_in[15];

    // ws layout: fp16 weights first (16B aligned), then fp32 state
    p.hW_ih_a   = (__half*)d_ws;                     //  2,097,152 halves
    p.hW_hh_a   = p.hW_ih_a   + 2097152;             // 16,777,216
    p.hW_sum    = p.hW_hh_a   + 16777216;            //  8,388,608
    p.hW_ih_hp  = p.hW_sum    + 8388608;             //  8,388,608
    p.hW_hh_hp  = p.hW_ih_hp  + 8388608;             // 67,108,864
    p.hW_out_a  = p.hW_hh_hp  + 67108864;            //    524,288
    p.hW_out_hp = p.hW_out_a  + 524288;              //  1,048,576
    float* ws = (float*)(p.hW_out_hp + 1048576);

    p.gates_a   = ws;           // 8192
    p.h_sum     = ws + 8192;    // 2048
    p.gacc      = ws + 10240;   // 16384
    p.h_a       = ws + 26624;   // 2048
    p.c_a0      = ws + 28672;   // 2048
    p.c_a1      = ws + 30720;   // 2048
    p.h_hp      = ws + 32768;   // 4096
    p.c_hp      = ws + 36864;   // 4096
    p.logits_a  = ws + 40960;   // 256
    p.logits_hp = ws + 41216;   // 256
    p.a_vec     = ws + 41472;   // 256
    p.out       = (float*)d_out;

    for (int t = 0; t < DEPTH; ++t) {
        kA<<<6720, 256, 0, stream>>>(p, t);
        kB<<<64, 256, 0, stream>>>(p, t);
        kC<<<1024, 256, 0, stream>>>(p, t);
    }
    kTail_gemv<<<64, 256, 0, stream>>>(p);
    kTail_softmax<<<1, 256, 0, stream>>>(p);
}